// Round 12
// baseline (132.477 us; speedup 1.0000x reference)
//
#include <hip/hip_runtime.h>

#define NF    50000
#define PADP  50001
#define KN    9
#define KTOT  2304
#define NCHUNK 782
#define BM2   256
#define NBLK2 196        // 196*256 = 50176 >= 50000
#define NKT   36         // 2304/64 K-tiles
#define BUF   32768      // one A dbuf: 256 rows x 128B
#define IDXOFF2 65536    // idx cache: 256*9*4 = 9216 -> LDS total 74752

// ---- ws layout (bytes) ----
#define WT_OFF   0u
#define FLAG_OFF 1179648u
#define CNT_OFF  1179904u
#define PADX_OFF 1183744u

typedef float f32x4 __attribute__((ext_vector_type(4)));
typedef __bf16 bf16x8 __attribute__((ext_vector_type(8)));

typedef const __attribute__((address_space(1))) unsigned int* gas_t;
typedef __attribute__((address_space(3))) unsigned int* las_t;

static __device__ __forceinline__ void gll16(const void* g, void* l) {
  __builtin_amdgcn_global_load_lds((gas_t)g, (las_t)l, 16, 0, 0);
}

static __device__ __forceinline__ unsigned short f2bf(float f) {
  unsigned int u = __builtin_bit_cast(unsigned int, f);
  u = u + 0x7fffu + ((u >> 16) & 1u);      // RNE
  return (unsigned short)(u >> 16);
}

// ---------- preprocessing (unchanged) ----------

__global__ void k_prep(const float* __restrict__ w, unsigned short* __restrict__ wt,
                       const unsigned char* __restrict__ pad, int* __restrict__ cnt,
                       const unsigned int* __restrict__ raw, int* __restrict__ flag) {
  if (blockIdx.x < 256) {
    int o = blockIdx.x;
    int i = threadIdx.x;
    const float* wr = w + (o * 256 + i) * 9;
    float wv[9];
    float s = 0.f;
#pragma unroll
    for (int k = 0; k < 9; ++k) { wv[k] = wr[k]; s += wv[k] * wv[k]; }
#pragma unroll
    for (int d = 32; d >= 1; d >>= 1) s += __shfl_xor(s, d);
    __shared__ float red[4];
    if ((i & 63) == 0) red[i >> 6] = s;
    __syncthreads();
    float dc = rsqrtf(red[0] + red[1] + red[2] + red[3] + 1e-8f);
#pragma unroll
    for (int k = 0; k < 9; ++k)
      wt[o * KTOT + k * 256 + i] = f2bf(wv[k] * dc);
  } else {
    int cb = blockIdx.x - 256;
    int t = cb * 256 + threadIdx.x;
    bool ip = (t < PADP) ? (pad[t] != 0) : true;
    unsigned long long m = __ballot(ip);
    int c = t >> 6;
    if ((threadIdx.x & 63) == 0 && c < NCHUNK) cnt[c] = __popcll(m);
    if (cb == 0 && threadIdx.x < 64) {
      unsigned int v = raw[threadIdx.x * 2 + 1];
      unsigned long long nz = __ballot(v != 0u);
      if (threadIdx.x == 0) flag[0] = (nz == 0ull) ? 1 : 0;
    }
  }
}

__global__ __launch_bounds__(256) void k_rankpadx(
    const float* __restrict__ x, const unsigned char* __restrict__ pad,
    const int* __restrict__ cnt, unsigned short* __restrict__ padx) {
  const int c = blockIdx.x;
  const int tid = threadIdx.x, w = tid >> 6, lane = tid & 63;
  int s = 0;
  for (int i = tid; i < c; i += 256) s += cnt[i];
#pragma unroll
  for (int d = 32; d >= 1; d >>= 1) s += __shfl_xor(s, d);
  __shared__ int red[4];
  __shared__ int rnk[64];
  if (lane == 0) red[w] = s;
  __syncthreads();
  const int S = red[0] + red[1] + red[2] + red[3];
  if (w == 0) {
    int p = c * 64 + lane;
    bool ip = (p < PADP) ? (pad[p] != 0) : true;
    unsigned long long m = __ballot(ip);
    int before = __popcll(m & ((1ull << lane) - 1ull));
    rnk[lane] = ip ? -1 : (p - (S + before));
  }
  __syncthreads();
  const int col = lane * 4;
#pragma unroll
  for (int i = 0; i < 16; ++i) {
    int rl = i * 4 + w;
    int pp = c * 64 + rl;
    if (pp >= PADP) continue;
    int rr = rnk[rl];
    ushort4 ov;
    if (rr < 0) { ov.x = 0; ov.y = 0; ov.z = 0; ov.w = 0; }
    else {
      const float4 v = *(const float4*)(x + rr * 256 + col);
      ov.x = f2bf(v.x); ov.y = f2bf(v.y); ov.z = f2bf(v.z); ov.w = f2bf(v.w);
    }
    *(ushort4*)(padx + pp * 256 + col) = ov;
  }
}

// ---------- main gathered GEMM: R11 4-phase skeleton + B-direct-to-register ----------
// BM=256 x BN=256 x BK=64, 512 thr (8 waves 2M x 4N), wave-tile 128x64 (acc 8x4).
// LDS: A-only dbuf 2 x 32KB + idx cache = 73KB. B: direct L2->register,
// 4 dwordx4/wave per issue point, 2-phase lead, compiler-managed waits.
// Per K-tile: P0 [dsA kk0 lo | B(kt,kk1)->set1 | gll16 HA0(kt+1); vmcnt(10)]
//             P1 [dsA kk0 hi | gll16 HA1(kt+1)]
//             P2 [dsA kk1 lo | B(kt+1,kk0)->set0]
//             P3 [dsA kk1 hi | idx refresh @ kt%4==2]
// Each phase: hdr -> s_barrier -> lgkmcnt(0) -> setprio(1) 16 MFMA -> s_barrier.
// LDS/K-tile: 131KB read + 32KB write ~= 640cy @256B/cy vs 620cy MFMA (cap ~97%).
__global__ __launch_bounds__(512, 2) void k_main(
    const unsigned short* __restrict__ padx,   // [50001][256] bf16
    const unsigned short* __restrict__ wt,     // [256][2304] bf16
    const void* __restrict__ nbr,              // [50000][9] int64 or int32
    const int* __restrict__ flag,
    const float* __restrict__ bias,            // [256]
    float* __restrict__ out) {                 // [50000][256] f32
  __shared__ __align__(16) unsigned char sm[74752];
  const int tid = threadIdx.x;
  const int wv = tid >> 6, lane = tid & 63;
  const int m0 = blockIdx.x * BM2;
  int* idxl = (int*)(sm + IDXOFF2);

  const int q = lane & 15, hi = lane >> 4;
  const int wm = wv >> 2, wn = wv & 3;

  float bv[4];
#pragma unroll
  for (int ni = 0; ni < 4; ++ni) bv[ni] = bias[wn * 64 + ni * 16 + q];

  // idx cache: 256 rows x 9 neighbors (clamped faces)
  const bool f64 = (flag[0] != 0);
  const long long* n64 = (const long long*)nbr;
  const int* n32 = (const int*)nbr;
  for (int e = tid; e < BM2 * 9; e += 512) {
    int f = m0 + e / 9;
    if (f >= NF) f = NF - 1;
    int k = e - (e / 9) * 9;
    idxl[e] = f64 ? (int)n64[f * KN + k] : n32[f * KN + k];
  }
  __syncthreads();

  // ---- A staging geometry (R11-verified) ----
  const int swsrc = ((tid & 7) ^ ((tid >> 3) & 7)) * 8;  // pre-swizzled src slot (elems)
  const int fl0 = tid >> 3;                              // staged row base 0..63
  const int rb0 = fl0 * 9, rb1 = (fl0 + 64) * 9, rb2 = (fl0 + 128) * 9, rb3 = (fl0 + 192) * 9;

  // ---- A fragment read offsets (bytes within a buf) ----
  const int q7 = q & 7;
  const int aof0 = wm * 16384 + q * 128 + ((hi    ) ^ q7) * 16;   // kk=0
  const int aof1 = wm * 16384 + q * 128 + ((4 + hi) ^ q7) * 16;   // kk=1

  // ---- B direct-load bases: lane (q,hi) reads wt[col][k + hi*8], 16B ----
  const unsigned short* wB0 = wt + (wn * 64 +  0 + q) * KTOT + hi * 8;
  const unsigned short* wB1 = wt + (wn * 64 + 16 + q) * KTOT + hi * 8;
  const unsigned short* wB2 = wt + (wn * 64 + 32 + q) * KTOT + hi * 8;
  const unsigned short* wB3 = wt + (wn * 64 + 48 + q) * KTOT + hi * 8;

  f32x4 acc[8][4];
#pragma unroll
  for (int a = 0; a < 8; ++a)
#pragma unroll
    for (int b = 0; b < 4; ++b) {
      acc[a][b][0] = 0.f; acc[a][b][1] = 0.f; acc[a][b][2] = 0.f; acc[a][b][3] = 0.f;
    }

  bf16x8 af[8], bq0[4], bq1[4];
  int pA0 = idxl[rb0], pA1 = idxl[rb1], pA2 = idxl[rb2], pA3 = idxl[rb3];

  // ---- prologue: B(0,kk0) -> set0; stage A(0) -> buf0; full drain ----
  bq0[0] = *(const bf16x8*)(wB0);
  bq0[1] = *(const bf16x8*)(wB1);
  bq0[2] = *(const bf16x8*)(wB2);
  bq0[3] = *(const bf16x8*)(wB3);
  gll16(padx + pA0 * 256 + swsrc, sm + tid * 16);
  gll16(padx + pA1 * 256 + swsrc, sm + 8192 + tid * 16);
  gll16(padx + pA2 * 256 + swsrc, sm + 16384 + tid * 16);
  gll16(padx + pA3 * 256 + swsrc, sm + 24576 + tid * 16);
  asm volatile("s_waitcnt vmcnt(0)" ::: "memory");
  __builtin_amdgcn_s_barrier();

#define LD(p) (*(const bf16x8*)(p))
#define SB __builtin_amdgcn_sched_barrier(0);
#define MF(MI, AFI, BQ) \
  acc[MI][0] = __builtin_amdgcn_mfma_f32_16x16x32_bf16(af[AFI], BQ[0], acc[MI][0], 0,0,0); \
  acc[MI][1] = __builtin_amdgcn_mfma_f32_16x16x32_bf16(af[AFI], BQ[1], acc[MI][1], 0,0,0); \
  acc[MI][2] = __builtin_amdgcn_mfma_f32_16x16x32_bf16(af[AFI], BQ[2], acc[MI][2], 0,0,0); \
  acc[MI][3] = __builtin_amdgcn_mfma_f32_16x16x32_bf16(af[AFI], BQ[3], acc[MI][3], 0,0,0);
#define TAIL(M0,M1,M2,M3,BQ) \
  SB __builtin_amdgcn_s_barrier(); \
  asm volatile("s_waitcnt lgkmcnt(0)" ::: "memory"); SB \
  __builtin_amdgcn_s_setprio(1); \
  MF(M0,M0,BQ) MF(M1,M1,BQ) MF(M2,M2,BQ) MF(M3,M3,BQ) \
  __builtin_amdgcn_s_setprio(0); \
  SB __builtin_amdgcn_s_barrier();

#pragma unroll 1
  for (int kt = 0; kt < NKT; ++kt) {
    const unsigned char* cb = sm + (kt & 1) * BUF;
    unsigned char* ob = (unsigned char*)sm + ((kt & 1) ^ 1) * BUF;
    const int c0n = ((kt + 1) & 3) * 64;     // channel offset of tile kt+1 in padx row
    // ---------- P0: dsA kk0 lo | B(kt,kk1)->set1 | stage HA0(kt+1) ----------
    af[0] = LD(cb + aof0);        af[1] = LD(cb + aof0 + 2048);
    af[2] = LD(cb + aof0 + 4096); af[3] = LD(cb + aof0 + 6144);
    {
      const int kb1 = kt * 64 + 32;
      bq1[0] = LD(wB0 + kb1); bq1[1] = LD(wB1 + kb1);
      bq1[2] = LD(wB2 + kb1); bq1[3] = LD(wB3 + kb1);
    }
    gll16(padx + pA0 * 256 + c0n + swsrc, ob + tid * 16);
    gll16(padx + pA1 * 256 + c0n + swsrc, ob + 8192 + tid * 16);
    SB
    asm volatile("s_waitcnt vmcnt(10)" ::: "memory");   // A(kt) resident
    TAIL(0,1,2,3,bq0)
    // ---------- P1: dsA kk0 hi | stage HA1(kt+1) ----------
    af[4] = LD(cb + aof0 + 8192);  af[5] = LD(cb + aof0 + 10240);
    af[6] = LD(cb + aof0 + 12288); af[7] = LD(cb + aof0 + 14336);
    gll16(padx + pA2 * 256 + c0n + swsrc, ob + 16384 + tid * 16);
    gll16(padx + pA3 * 256 + c0n + swsrc, ob + 24576 + tid * 16);
    TAIL(4,5,6,7,bq0)
    // ---------- P2: dsA kk1 lo | B(kt+1,kk0)->set0 ----------
    af[0] = LD(cb + aof1);        af[1] = LD(cb + aof1 + 2048);
    af[2] = LD(cb + aof1 + 4096); af[3] = LD(cb + aof1 + 6144);
    {
      const int kb0 = ((kt + 1 < NKT) ? kt + 1 : NKT - 1) * 64;
      bq0[0] = LD(wB0 + kb0); bq0[1] = LD(wB1 + kb0);
      bq0[2] = LD(wB2 + kb0); bq0[3] = LD(wB3 + kb0);
    }
    TAIL(0,1,2,3,bq1)
    // ---------- P3: dsA kk1 hi | idx refresh every 4th kt ----------
    af[4] = LD(cb + aof1 + 8192);  af[5] = LD(cb + aof1 + 10240);
    af[6] = LD(cb + aof1 + 12288); af[7] = LD(cb + aof1 + 14336);
    if ((kt & 3) == 2) {
      int gn = (kt >> 2) + 1; if (gn > 8) gn = 8;
      pA0 = idxl[rb0 + gn]; pA1 = idxl[rb1 + gn];
      pA2 = idxl[rb2 + gn]; pA3 = idxl[rb3 + gn];
    }
    TAIL(4,5,6,7,bq1)
  }
#undef TAIL
#undef MF
#undef LD
#undef SB
  asm volatile("s_waitcnt vmcnt(0)" ::: "memory");

  // ---- epilogue: bias + store (D: col = q, row = hi*4 + rr) ----
#pragma unroll
  for (int ni = 0; ni < 4; ++ni) {
    const int col = wn * 64 + ni * 16 + q;
#pragma unroll
    for (int mi = 0; mi < 8; ++mi) {
#pragma unroll
      for (int rr = 0; rr < 4; ++rr) {
        const int row = m0 + wm * 128 + mi * 16 + hi * 4 + rr;
        if (row < NF) out[row * 256 + col] = acc[mi][ni][rr] + bv[ni];
      }
    }
  }
}

extern "C" void kernel_launch(void* const* d_in, const int* in_sizes, int n_in,
                              void* d_out, int out_size, void* d_ws, size_t ws_size,
                              hipStream_t stream) {
  const float* x = (const float*)d_in[0];
  const float* wfull = (const float*)d_in[1];
  const float* bias = (const float*)d_in[2];
  const void* nbr = d_in[3];
  const unsigned char* pad = (const unsigned char*)d_in[4];
  float* out = (float*)d_out;
  char* ws = (char*)d_ws;

  unsigned short* wt   = (unsigned short*)(ws + WT_OFF);
  int* flag            = (int*)(ws + FLAG_OFF);
  int* cnt             = (int*)(ws + CNT_OFF);
  unsigned short* padx = (unsigned short*)(ws + PADX_OFF);

  k_prep<<<452, 256, 0, stream>>>(wfull, wt, pad, cnt, (const unsigned int*)nbr, flag);
  k_rankpadx<<<NCHUNK, 256, 0, stream>>>(x, pad, cnt, padx);
  k_main<<<NBLK2, 512, 0, stream>>>(padx, wt, nbr, flag, bias, out);
}

// Round 13
// 108.647 us; speedup vs baseline: 1.2193x; 1.2193x over previous
//
#include <hip/hip_runtime.h>

#define NF    50000
#define PADP  50001
#define KN    9
#define KTOT  2304
#define NCHUNK 782
#define BM2   256
#define NBLK2 196        // 196*256 = 50176 >= 50000
#define NKT   36         // 2304/64 K-tiles
#define ABUF  32768      // one A buffer: 256 rows x 128B
#define BBASE 98304      // B dbuf region: 2 x 32KB at 98304 / 131072

// ---- ws layout (bytes) ----
#define WT_OFF   0u
#define FLAG_OFF 1179648u
#define CNT_OFF  1179904u
#define PADX_OFF 1183744u

typedef float f32x4 __attribute__((ext_vector_type(4)));
typedef __bf16 bf16x8 __attribute__((ext_vector_type(8)));

typedef const __attribute__((address_space(1))) unsigned int* gas_t;
typedef __attribute__((address_space(3))) unsigned int* las_t;

static __device__ __forceinline__ void gll16(const void* g, void* l) {
  __builtin_amdgcn_global_load_lds((gas_t)g, (las_t)l, 16, 0, 0);
}

static __device__ __forceinline__ unsigned short f2bf(float f) {
  unsigned int u = __builtin_bit_cast(unsigned int, f);
  u = u + 0x7fffu + ((u >> 16) & 1u);      // RNE
  return (unsigned short)(u >> 16);
}

// ---------- preprocessing (unchanged) ----------

__global__ void k_prep(const float* __restrict__ w, unsigned short* __restrict__ wt,
                       const unsigned char* __restrict__ pad, int* __restrict__ cnt,
                       const unsigned int* __restrict__ raw, int* __restrict__ flag) {
  if (blockIdx.x < 256) {
    int o = blockIdx.x;
    int i = threadIdx.x;
    const float* wr = w + (o * 256 + i) * 9;
    float wv[9];
    float s = 0.f;
#pragma unroll
    for (int k = 0; k < 9; ++k) { wv[k] = wr[k]; s += wv[k] * wv[k]; }
#pragma unroll
    for (int d = 32; d >= 1; d >>= 1) s += __shfl_xor(s, d);
    __shared__ float red[4];
    if ((i & 63) == 0) red[i >> 6] = s;
    __syncthreads();
    float dc = rsqrtf(red[0] + red[1] + red[2] + red[3] + 1e-8f);
#pragma unroll
    for (int k = 0; k < 9; ++k)
      wt[o * KTOT + k * 256 + i] = f2bf(wv[k] * dc);
  } else {
    int cb = blockIdx.x - 256;
    int t = cb * 256 + threadIdx.x;
    bool ip = (t < PADP) ? (pad[t] != 0) : true;
    unsigned long long m = __ballot(ip);
    int c = t >> 6;
    if ((threadIdx.x & 63) == 0 && c < NCHUNK) cnt[c] = __popcll(m);
    if (cb == 0 && threadIdx.x < 64) {
      unsigned int v = raw[threadIdx.x * 2 + 1];
      unsigned long long nz = __ballot(v != 0u);
      if (threadIdx.x == 0) flag[0] = (nz == 0ull) ? 1 : 0;
    }
  }
}

__global__ __launch_bounds__(256) void k_rankpadx(
    const float* __restrict__ x, const unsigned char* __restrict__ pad,
    const int* __restrict__ cnt, unsigned short* __restrict__ padx) {
  const int c = blockIdx.x;
  const int tid = threadIdx.x, w = tid >> 6, lane = tid & 63;
  int s = 0;
  for (int i = tid; i < c; i += 256) s += cnt[i];
#pragma unroll
  for (int d = 32; d >= 1; d >>= 1) s += __shfl_xor(s, d);
  __shared__ int red[4];
  __shared__ int rnk[64];
  if (lane == 0) red[w] = s;
  __syncthreads();
  const int S = red[0] + red[1] + red[2] + red[3];
  if (w == 0) {
    int p = c * 64 + lane;
    bool ip = (p < PADP) ? (pad[p] != 0) : true;
    unsigned long long m = __ballot(ip);
    int before = __popcll(m & ((1ull << lane) - 1ull));
    rnk[lane] = ip ? -1 : (p - (S + before));
  }
  __syncthreads();
  const int col = lane * 4;
#pragma unroll
  for (int i = 0; i < 16; ++i) {
    int rl = i * 4 + w;
    int pp = c * 64 + rl;
    if (pp >= PADP) continue;
    int rr = rnk[rl];
    ushort4 ov;
    if (rr < 0) { ov.x = 0; ov.y = 0; ov.z = 0; ov.w = 0; }
    else {
      const float4 v = *(const float4*)(x + rr * 256 + col);
      ov.x = f2bf(v.x); ov.y = f2bf(v.y); ov.z = f2bf(v.z); ov.w = f2bf(v.w);
    }
    *(ushort4*)(padx + pp * 256 + col) = ov;
  }
}

// ---------- main gathered GEMM: R11 geometry, corrected wait schedule ----------
// BM=256 x BN=256 x BK=64, 512 thr (8 waves 2M x 4N), wave-tile 128x64 (acc 8x4).
// LDS: A ring-3 x 32KB + B dbuf 2 x 32KB = 160KiB exactly. idx in registers.
// Per K-tile (4 phases x 16 MFMA):
//  P0: dsA kk0 lo x4 + dsB kk0 x4 | gll16 B(kt+1)->B-other x4
//  P1: dsA kk0 hi x4              | gll16 A(kt+2)->A-third x4 | idx refresh @kt%4==1
//  P2: dsA kk1 lo x4 + dsB kk1 x4
//  P3: dsA kk1 hi x4 | vmcnt(4)  <- residency of A(kt+1)+B(kt+1) ONE K-tile
//                                   before first read (fixes R11's mid-phase wait)
// Flights: A staged kt-1 P1 -> waited kt P3 = 7 phases (>> 900cy HBM tail);
// B 3 phases (L2-sequential). Every LDS overwrite >= 2 barriers after last read.
__global__ __launch_bounds__(512, 1) void k_main(
    const unsigned short* __restrict__ padx,   // [50001][256] bf16
    const unsigned short* __restrict__ wt,     // [256][2304] bf16
    const void* __restrict__ nbr,              // [50000][9] int64 or int32
    const int* __restrict__ flag,
    const float* __restrict__ bias,            // [256]
    float* __restrict__ out) {                 // [50000][256] f32
  __shared__ __align__(16) unsigned char sm[163840];
  const int tid = threadIdx.x;
  const int wv = tid >> 6, lane = tid & 63;
  const int m0 = blockIdx.x * BM2;

  const int q = lane & 15, hi = lane >> 4;
  const int wm = wv >> 2, wn = wv & 3;

  float bv[4];
#pragma unroll
  for (int ni = 0; ni < 4; ++ni) bv[ni] = bias[wn * 64 + ni * 16 + q];

  // ---- per-thread gather indices (4 staged rows), direct from global ----
  const bool f64 = (flag[0] != 0);
  const char* nb = (const char*)nbr;
  const int fl0 = tid >> 3;
  int fr0 = m0 + fl0, fr1 = m0 + fl0 + 64, fr2 = m0 + fl0 + 128, fr3 = m0 + fl0 + 192;
  if (fr0 > NF - 1) fr0 = NF - 1;
  if (fr1 > NF - 1) fr1 = NF - 1;
  if (fr2 > NF - 1) fr2 = NF - 1;
  if (fr3 > NF - 1) fr3 = NF - 1;
#define LDIDX(fr, gg) (f64 ? (int)*(const long long*)(nb + ((fr) * 9 + (gg)) * 8) \
                           : *(const int*)(nb + ((fr) * 9 + (gg)) * 4))
  int pc0 = LDIDX(fr0, 0), pc1 = LDIDX(fr1, 0), pc2 = LDIDX(fr2, 0), pc3 = LDIDX(fr3, 0);
  int pn0 = pc0, pn1 = pc1, pn2 = pc2, pn3 = pc3;

  // ---- staging geometry (R11-verified source-side swizzle) ----
  const int swsrc = ((tid & 7) ^ ((tid >> 3) & 7)) * 8;
  const unsigned short* wtb00 = wt + (fl0      ) * KTOT + swsrc;
  const unsigned short* wtb01 = wt + (fl0 +  64) * KTOT + swsrc;
  const unsigned short* wtb10 = wt + (fl0 + 128) * KTOT + swsrc;
  const unsigned short* wtb11 = wt + (fl0 + 192) * KTOT + swsrc;
  const int dst16 = tid * 16;

  // ---- fragment read offsets (relative, buffer base added per iter) ----
  const int q7 = q & 7;
  const int aofs0 = wm * 16384 + q * 128 + ((hi    ) ^ q7) * 16;   // kk=0
  const int aofs1 = wm * 16384 + q * 128 + ((4 + hi) ^ q7) * 16;   // kk=1
  const int bofs0 = (wn * 64 + q) * 128 + ((hi    ) ^ q7) * 16;
  const int bofs1 = (wn * 64 + q) * 128 + ((4 + hi) ^ q7) * 16;

  f32x4 acc[8][4];
#pragma unroll
  for (int a = 0; a < 8; ++a)
#pragma unroll
    for (int b = 0; b < 4; ++b) {
      acc[a][b][0] = 0.f; acc[a][b][1] = 0.f; acc[a][b][2] = 0.f; acc[a][b][3] = 0.f;
    }

  // ---- prologue: stage A(0)->buf0, A(1)->buf1, B(0)->Bbuf0; full drain ----
  gll16(padx + pc0 * 256 +  0 + swsrc, sm + dst16);
  gll16(padx + pc1 * 256 +  0 + swsrc, sm + 8192 + dst16);
  gll16(padx + pc2 * 256 +  0 + swsrc, sm + 16384 + dst16);
  gll16(padx + pc3 * 256 +  0 + swsrc, sm + 24576 + dst16);
  gll16(padx + pc0 * 256 + 64 + swsrc, sm + ABUF + dst16);
  gll16(padx + pc1 * 256 + 64 + swsrc, sm + ABUF + 8192 + dst16);
  gll16(padx + pc2 * 256 + 64 + swsrc, sm + ABUF + 16384 + dst16);
  gll16(padx + pc3 * 256 + 64 + swsrc, sm + ABUF + 24576 + dst16);
  gll16(wtb00, sm + BBASE + dst16);
  gll16(wtb01, sm + BBASE + 8192 + dst16);
  gll16(wtb10, sm + BBASE + 16384 + dst16);
  gll16(wtb11, sm + BBASE + 24576 + dst16);
  asm volatile("s_waitcnt vmcnt(0)" ::: "memory");
  __builtin_amdgcn_s_barrier();

  bf16x8 af[4], bq[4];
  int aCur = 0, aNext = ABUF, aThird = 2 * ABUF;
  int bCur = BBASE, bOth = BBASE + ABUF;

#define LD(p) (*(const bf16x8*)(p))
#define SB __builtin_amdgcn_sched_barrier(0);
#define MF(MI) \
  acc[MI][0] = __builtin_amdgcn_mfma_f32_16x16x32_bf16(af[(MI)&3], bq[0], acc[MI][0], 0,0,0); \
  acc[MI][1] = __builtin_amdgcn_mfma_f32_16x16x32_bf16(af[(MI)&3], bq[1], acc[MI][1], 0,0,0); \
  acc[MI][2] = __builtin_amdgcn_mfma_f32_16x16x32_bf16(af[(MI)&3], bq[2], acc[MI][2], 0,0,0); \
  acc[MI][3] = __builtin_amdgcn_mfma_f32_16x16x32_bf16(af[(MI)&3], bq[3], acc[MI][3], 0,0,0);
#define TAIL(M0,M1,M2,M3) \
  SB __builtin_amdgcn_s_barrier(); \
  asm volatile("s_waitcnt lgkmcnt(0)" ::: "memory"); SB \
  __builtin_amdgcn_s_setprio(1); \
  MF(M0) MF(M1) MF(M2) MF(M3) \
  __builtin_amdgcn_s_setprio(0); \
  SB __builtin_amdgcn_s_barrier();

#pragma unroll 1
  for (int kt = 0; kt < NKT; ++kt) {
    const int g = kt >> 2;
    // ---------- P0: dsA kk0 lo + dsB kk0 | stage B(kt+1) -> bOth ----------
    af[0] = LD(sm + aCur + aofs0);        af[1] = LD(sm + aCur + aofs0 + 2048);
    af[2] = LD(sm + aCur + aofs0 + 4096); af[3] = LD(sm + aCur + aofs0 + 6144);
    bq[0] = LD(sm + bCur + bofs0);        bq[1] = LD(sm + bCur + bofs0 + 2048);
    bq[2] = LD(sm + bCur + bofs0 + 4096); bq[3] = LD(sm + bCur + bofs0 + 6144);
    {
      const int kb = ((kt + 1 < NKT) ? kt + 1 : NKT - 1) * 64;
      gll16(wtb00 + kb, sm + bOth + dst16);
      gll16(wtb01 + kb, sm + bOth + 8192 + dst16);
      gll16(wtb10 + kb, sm + bOth + 16384 + dst16);
      gll16(wtb11 + kb, sm + bOth + 24576 + dst16);
    }
    TAIL(0,1,2,3)
    // ---------- P1: dsA kk0 hi | stage A(kt+2) -> aThird | idx refresh ----------
    af[0] = LD(sm + aCur + aofs0 + 8192);  af[1] = LD(sm + aCur + aofs0 + 10240);
    af[2] = LD(sm + aCur + aofs0 + 12288); af[3] = LD(sm + aCur + aofs0 + 14336);
    {
      const int u = kt + 2;
      const int gu = u >> 2;
      const int c0 = (u & 3) * 64;
      const int s0 = (gu == g) ? pc0 : pn0;
      const int s1 = (gu == g) ? pc1 : pn1;
      const int s2 = (gu == g) ? pc2 : pn2;
      const int s3 = (gu == g) ? pc3 : pn3;
      gll16(padx + s0 * 256 + c0 + swsrc, sm + aThird + dst16);
      gll16(padx + s1 * 256 + c0 + swsrc, sm + aThird + 8192 + dst16);
      gll16(padx + s2 * 256 + c0 + swsrc, sm + aThird + 16384 + dst16);
      gll16(padx + s3 * 256 + c0 + swsrc, sm + aThird + 24576 + dst16);
    }
    if ((kt & 3) == 1) {
      const int gn = (g + 1 > 8) ? 8 : g + 1;
      pn0 = LDIDX(fr0, gn); pn1 = LDIDX(fr1, gn);
      pn2 = LDIDX(fr2, gn); pn3 = LDIDX(fr3, gn);
    }
    TAIL(4,5,6,7)
    // ---------- P2: dsA kk1 lo + dsB kk1 ----------
    af[0] = LD(sm + aCur + aofs1);        af[1] = LD(sm + aCur + aofs1 + 2048);
    af[2] = LD(sm + aCur + aofs1 + 4096); af[3] = LD(sm + aCur + aofs1 + 6144);
    bq[0] = LD(sm + bCur + bofs1);        bq[1] = LD(sm + bCur + bofs1 + 2048);
    bq[2] = LD(sm + bCur + bofs1 + 4096); bq[3] = LD(sm + bCur + bofs1 + 6144);
    TAIL(0,1,2,3)
    // ---------- P3: dsA kk1 hi | vmcnt(4): A(kt+1),B(kt+1) resident ----------
    af[0] = LD(sm + aCur + aofs1 + 8192);  af[1] = LD(sm + aCur + aofs1 + 10240);
    af[2] = LD(sm + aCur + aofs1 + 12288); af[3] = LD(sm + aCur + aofs1 + 14336);
    SB
    asm volatile("s_waitcnt vmcnt(4)" ::: "memory");
    TAIL(4,5,6,7)
    // rotations
    { int t0 = aCur; aCur = aNext; aNext = aThird; aThird = t0; }
    { int t1 = bCur; bCur = bOth; bOth = t1; }
    if ((kt & 3) == 3) { pc0 = pn0; pc1 = pn1; pc2 = pn2; pc3 = pn3; }
  }
#undef TAIL
#undef MF
#undef LD
#undef SB
#undef LDIDX
  asm volatile("s_waitcnt vmcnt(0)" ::: "memory");

  // ---- epilogue: bias + store (D: col = q, row = hi*4 + rr) ----
#pragma unroll
  for (int ni = 0; ni < 4; ++ni) {
    const int col = wn * 64 + ni * 16 + q;
#pragma unroll
    for (int mi = 0; mi < 8; ++mi) {
#pragma unroll
      for (int rr = 0; rr < 4; ++rr) {
        const int row = m0 + wm * 128 + mi * 16 + hi * 4 + rr;
        if (row < NF) out[row * 256 + col] = acc[mi][ni][rr] + bv[ni];
      }
    }
  }
}

extern "C" void kernel_launch(void* const* d_in, const int* in_sizes, int n_in,
                              void* d_out, int out_size, void* d_ws, size_t ws_size,
                              hipStream_t stream) {
  const float* x = (const float*)d_in[0];
  const float* wfull = (const float*)d_in[1];
  const float* bias = (const float*)d_in[2];
  const void* nbr = d_in[3];
  const unsigned char* pad = (const unsigned char*)d_in[4];
  float* out = (float*)d_out;
  char* ws = (char*)d_ws;

  unsigned short* wt   = (unsigned short*)(ws + WT_OFF);
  int* flag            = (int*)(ws + FLAG_OFF);
  int* cnt             = (int*)(ws + CNT_OFF);
  unsigned short* padx = (unsigned short*)(ws + PADX_OFF);

  k_prep<<<452, 256, 0, stream>>>(wfull, wt, pad, cnt, (const unsigned int*)nbr, flag);
  k_rankpadx<<<NCHUNK, 256, 0, stream>>>(x, pad, cnt, padx);
  k_main<<<NBLK2, 512, 0, stream>>>(padx, wt, nbr, flag, bias, out);
}

// Round 14
// 85.985 us; speedup vs baseline: 1.5407x; 1.2636x over previous
//
#include <hip/hip_runtime.h>

#define NF    50000
#define PADP  50001
#define KN    9
#define KTOT  2304
#define NCHUNK 782
#define BM3   224
#define NBLK3 224        // 224*224 = 50176 >= 50000; single round
#define NKT   36         // 2304/64 K-tiles
#define ABUF  28672      // one A buffer: 224 rows x 128B
#define BB    86016      // B dbuf base (2 x 32768)
#define IDXO  151552     // idx cache 224*9*4 = 8064 -> total 159616

// ---- ws layout (bytes) ----
#define WT_OFF   0u
#define FLAG_OFF 1179648u
#define CNT_OFF  1179904u
#define PADX_OFF 1183744u

typedef float f32x4 __attribute__((ext_vector_type(4)));
typedef __bf16 bf16x8 __attribute__((ext_vector_type(8)));

typedef const __attribute__((address_space(1))) unsigned int* gas_t;
typedef __attribute__((address_space(3))) unsigned int* las_t;

static __device__ __forceinline__ void gll16(const void* g, void* l) {
  __builtin_amdgcn_global_load_lds((gas_t)g, (las_t)l, 16, 0, 0);
}

static __device__ __forceinline__ unsigned short f2bf(float f) {
  unsigned int u = __builtin_bit_cast(unsigned int, f);
  u = u + 0x7fffu + ((u >> 16) & 1u);      // RNE
  return (unsigned short)(u >> 16);
}

// ---------- preprocessing (unchanged) ----------

__global__ void k_prep(const float* __restrict__ w, unsigned short* __restrict__ wt,
                       const unsigned char* __restrict__ pad, int* __restrict__ cnt,
                       const unsigned int* __restrict__ raw, int* __restrict__ flag) {
  if (blockIdx.x < 256) {
    int o = blockIdx.x;
    int i = threadIdx.x;
    const float* wr = w + (o * 256 + i) * 9;
    float wv[9];
    float s = 0.f;
#pragma unroll
    for (int k = 0; k < 9; ++k) { wv[k] = wr[k]; s += wv[k] * wv[k]; }
#pragma unroll
    for (int d = 32; d >= 1; d >>= 1) s += __shfl_xor(s, d);
    __shared__ float red[4];
    if ((i & 63) == 0) red[i >> 6] = s;
    __syncthreads();
    float dc = rsqrtf(red[0] + red[1] + red[2] + red[3] + 1e-8f);
#pragma unroll
    for (int k = 0; k < 9; ++k)
      wt[o * KTOT + k * 256 + i] = f2bf(wv[k] * dc);
  } else {
    int cb = blockIdx.x - 256;
    int t = cb * 256 + threadIdx.x;
    bool ip = (t < PADP) ? (pad[t] != 0) : true;
    unsigned long long m = __ballot(ip);
    int c = t >> 6;
    if ((threadIdx.x & 63) == 0 && c < NCHUNK) cnt[c] = __popcll(m);
    if (cb == 0 && threadIdx.x < 64) {
      unsigned int v = raw[threadIdx.x * 2 + 1];
      unsigned long long nz = __ballot(v != 0u);
      if (threadIdx.x == 0) flag[0] = (nz == 0ull) ? 1 : 0;
    }
  }
}

__global__ __launch_bounds__(256) void k_rankpadx(
    const float* __restrict__ x, const unsigned char* __restrict__ pad,
    const int* __restrict__ cnt, unsigned short* __restrict__ padx) {
  const int c = blockIdx.x;
  const int tid = threadIdx.x, w = tid >> 6, lane = tid & 63;
  int s = 0;
  for (int i = tid; i < c; i += 256) s += cnt[i];
#pragma unroll
  for (int d = 32; d >= 1; d >>= 1) s += __shfl_xor(s, d);
  __shared__ int red[4];
  __shared__ int rnk[64];
  if (lane == 0) red[w] = s;
  __syncthreads();
  const int S = red[0] + red[1] + red[2] + red[3];
  if (w == 0) {
    int p = c * 64 + lane;
    bool ip = (p < PADP) ? (pad[p] != 0) : true;
    unsigned long long m = __ballot(ip);
    int before = __popcll(m & ((1ull << lane) - 1ull));
    rnk[lane] = ip ? -1 : (p - (S + before));
  }
  __syncthreads();
  const int col = lane * 4;
#pragma unroll
  for (int i = 0; i < 16; ++i) {
    int rl = i * 4 + w;
    int pp = c * 64 + rl;
    if (pp >= PADP) continue;
    int rr = rnk[rl];
    ushort4 ov;
    if (rr < 0) { ov.x = 0; ov.y = 0; ov.z = 0; ov.w = 0; }
    else {
      const float4 v = *(const float4*)(x + rr * 256 + col);
      ov.x = f2bf(v.x); ov.y = f2bf(v.y); ov.z = f2bf(v.z); ov.w = f2bf(v.w);
    }
    *(ushort4*)(padx + pp * 256 + col) = ov;
  }
}

// ---------- main gathered GEMM: 2-phase, BM=224, A ring-3 + B dbuf ----------
// BM=224 x BN=256 x BK=64, 512 thr (8 waves 2M x 4N), wave-tile 112x64 (7x4 acc).
// LDS: A ring-3 x 28KB + B dbuf 2 x 32KB + idx = 156KB. Grid 224 (1 round).
// Per K-tile, TWO phases (28 MFMA each; halves barrier events vs R11):
//  P0: ds 7A+4B (kk0) | stage B(kt+1)->B-other (4 gll16, all) | [idx refresh]
//  P1: ds 7A+4B (kk1) | stage A(kt+2)->A-stage (4 gll16, waves 0-6)
//      | vmcnt(4) waves0-6 (leaves A(kt+2)) / vmcnt(0) wave7 (drains its B writes)
// Each phase tail: barrier -> lgkmcnt(0) -> setprio(1) 28 MFMA -> barrier.
// Hazards: every LDS overwrite >= 2 barriers after its last reader (A-stage
// target holds A(kt-1), last read kt-1 P1; B-other holds B(kt-1), last read kt-1 P1).
__global__ __launch_bounds__(512, 1) void k_main(
    const unsigned short* __restrict__ padx,   // [50001][256] bf16
    const unsigned short* __restrict__ wt,     // [256][2304] bf16
    const void* __restrict__ nbr,              // [50000][9] int64 or int32
    const int* __restrict__ flag,
    const float* __restrict__ bias,            // [256]
    float* __restrict__ out) {                 // [50000][256] f32
  __shared__ __align__(16) unsigned char sm[159616];
  const int tid = threadIdx.x;
  const int wv = tid >> 6, lane = tid & 63;
  const int m0 = blockIdx.x * BM3;
  int* idxl = (int*)(sm + IDXO);

  const int q = lane & 15, hi = lane >> 4;
  const int wm = wv >> 2, wn = wv & 3;

  float bv[4];
#pragma unroll
  for (int ni = 0; ni < 4; ++ni) bv[ni] = bias[wn * 64 + ni * 16 + q];

  // idx cache: 224 rows x 9 neighbors (clamped faces)
  const bool f64 = (flag[0] != 0);
  const long long* n64 = (const long long*)nbr;
  const int* n32 = (const int*)nbr;
  for (int e = tid; e < BM3 * 9; e += 512) {
    int f = m0 + e / 9;
    if (f >= NF) f = NF - 1;
    int k = e - (e / 9) * 9;
    idxl[e] = f64 ? (int)n64[f * KN + k] : n32[f * KN + k];
  }
  __syncthreads();

  // ---- staging geometry ----
  const int swsrc = ((tid & 7) ^ ((tid >> 3) & 7)) * 8;  // pre-swizzled src slot (elems)
  const int dst16 = tid * 16;
  // A: waves 0-6 (tid<448), 4 instr, instr j covers rows j*56 + (tid>>3)
  int rr0 = 0, rr1 = 0, rr2 = 0, rr3 = 0;
  if (tid < 448) {
    rr0 = (tid >> 3);            // + 0*56
    rr1 = rr0 + 56; rr2 = rr0 + 112; rr3 = rr0 + 168;
  }
  // B: all 512 threads, 4 instr, rows (tid>>3) + {0,64,128,192}
  const int fl0 = tid >> 3;
  const unsigned short* wtb00 = wt + (fl0      ) * KTOT + swsrc;
  const unsigned short* wtb01 = wt + (fl0 +  64) * KTOT + swsrc;
  const unsigned short* wtb10 = wt + (fl0 + 128) * KTOT + swsrc;
  const unsigned short* wtb11 = wt + (fl0 + 192) * KTOT + swsrc;

  // ---- fragment read offsets ----
  const int q7 = q & 7;
  const int s0 = ((hi    ) ^ q7) * 16;   // kk=0 slot
  const int s1 = ((4 + hi) ^ q7) * 16;   // kk=1 slot
  int aoffb[7], bofb[4];
#pragma unroll
  for (int mi = 0; mi < 7; ++mi) aoffb[mi] = (wm * 112 + mi * 16 + q) * 128;
#pragma unroll
  for (int ni = 0; ni < 4; ++ni) bofb[ni] = (wn * 64 + ni * 16 + q) * 128;

  f32x4 acc[7][4];
#pragma unroll
  for (int a = 0; a < 7; ++a)
#pragma unroll
    for (int b = 0; b < 4; ++b) {
      acc[a][b][0] = 0.f; acc[a][b][1] = 0.f; acc[a][b][2] = 0.f; acc[a][b][3] = 0.f;
    }

  // per-thread gather indices for the 4 staged rows (from LDS -> no vmem)
  int pc0 = 0, pc1 = 0, pc2 = 0, pc3 = 0, pn0 = 0, pn1 = 0, pn2 = 0, pn3 = 0;
  if (tid < 448) {
    pc0 = idxl[rr0 * 9]; pc1 = idxl[rr1 * 9]; pc2 = idxl[rr2 * 9]; pc3 = idxl[rr3 * 9];
    pn0 = pc0; pn1 = pc1; pn2 = pc2; pn3 = pc3;
  }

  // ---- prologue: A(0)->Ab0, A(1)->Ab1, B(0)->Bb0; drain; barrier ----
  if (tid < 448) {
    gll16(padx + pc0 * 256 +  0 + swsrc, sm + dst16);
    gll16(padx + pc1 * 256 +  0 + swsrc, sm + 7168 + dst16);
    gll16(padx + pc2 * 256 +  0 + swsrc, sm + 14336 + dst16);
    gll16(padx + pc3 * 256 +  0 + swsrc, sm + 21504 + dst16);
    gll16(padx + pc0 * 256 + 64 + swsrc, sm + ABUF + dst16);
    gll16(padx + pc1 * 256 + 64 + swsrc, sm + ABUF + 7168 + dst16);
    gll16(padx + pc2 * 256 + 64 + swsrc, sm + ABUF + 14336 + dst16);
    gll16(padx + pc3 * 256 + 64 + swsrc, sm + ABUF + 21504 + dst16);
  }
  gll16(wtb00, sm + BB + dst16);
  gll16(wtb01, sm + BB + 8192 + dst16);
  gll16(wtb10, sm + BB + 16384 + dst16);
  gll16(wtb11, sm + BB + 24576 + dst16);
  asm volatile("s_waitcnt vmcnt(0)" ::: "memory");
  __builtin_amdgcn_s_barrier();

  bf16x8 af[7], bq[4];
  int aC = 0, aN = ABUF, aS = 2 * ABUF;
  int bC = BB, bO = BB + 32768;

#define LD(p) (*(const bf16x8*)(p))
#define SB __builtin_amdgcn_sched_barrier(0);
#define MF(MI) \
  acc[MI][0] = __builtin_amdgcn_mfma_f32_16x16x32_bf16(af[MI], bq[0], acc[MI][0], 0,0,0); \
  acc[MI][1] = __builtin_amdgcn_mfma_f32_16x16x32_bf16(af[MI], bq[1], acc[MI][1], 0,0,0); \
  acc[MI][2] = __builtin_amdgcn_mfma_f32_16x16x32_bf16(af[MI], bq[2], acc[MI][2], 0,0,0); \
  acc[MI][3] = __builtin_amdgcn_mfma_f32_16x16x32_bf16(af[MI], bq[3], acc[MI][3], 0,0,0);
#define TAIL28 \
  SB __builtin_amdgcn_s_barrier(); \
  asm volatile("s_waitcnt lgkmcnt(0)" ::: "memory"); SB \
  __builtin_amdgcn_s_setprio(1); \
  MF(0) MF(1) MF(2) MF(3) MF(4) MF(5) MF(6) \
  __builtin_amdgcn_s_setprio(0); \
  SB __builtin_amdgcn_s_barrier();

#pragma unroll 1
  for (int kt = 0; kt < NKT; ++kt) {
    // ---------- P0: ds kk0 (7A + 4B) | stage B(kt+1)->bO | idx refresh ----------
#pragma unroll
    for (int mi = 0; mi < 7; ++mi) af[mi] = LD(sm + aC + aoffb[mi] + s0);
#pragma unroll
    for (int ni = 0; ni < 4; ++ni) bq[ni] = LD(sm + bC + bofb[ni] + s0);
    {
      const int kb = ((kt + 1 < NKT) ? kt + 1 : NKT - 1) * 64;
      gll16(wtb00 + kb, sm + bO + dst16);
      gll16(wtb01 + kb, sm + bO + 8192 + dst16);
      gll16(wtb10 + kb, sm + bO + 16384 + dst16);
      gll16(wtb11 + kb, sm + bO + 24576 + dst16);
    }
    if ((kt & 3) == 1 && tid < 448) {
      int gn = (kt >> 2) + 1; if (gn > 8) gn = 8;
      pn0 = idxl[rr0 * 9 + gn]; pn1 = idxl[rr1 * 9 + gn];
      pn2 = idxl[rr2 * 9 + gn]; pn3 = idxl[rr3 * 9 + gn];
    }
    TAIL28
    // ---------- P1: ds kk1 (7A + 4B) | stage A(kt+2)->aS | counted vmcnt ----------
#pragma unroll
    for (int mi = 0; mi < 7; ++mi) af[mi] = LD(sm + aC + aoffb[mi] + s1);
#pragma unroll
    for (int ni = 0; ni < 4; ++ni) bq[ni] = LD(sm + bC + bofb[ni] + s1);
    SB
    if (tid < 448) {
      const int c0 = ((kt + 2) & 3) * 64;
      const int u0 = ((kt & 3) < 2) ? pc0 : pn0;
      const int u1 = ((kt & 3) < 2) ? pc1 : pn1;
      const int u2 = ((kt & 3) < 2) ? pc2 : pn2;
      const int u3 = ((kt & 3) < 2) ? pc3 : pn3;
      gll16(padx + u0 * 256 + c0 + swsrc, sm + aS + dst16);
      gll16(padx + u1 * 256 + c0 + swsrc, sm + aS + 7168 + dst16);
      gll16(padx + u2 * 256 + c0 + swsrc, sm + aS + 14336 + dst16);
      gll16(padx + u3 * 256 + c0 + swsrc, sm + aS + 21504 + dst16);
      asm volatile("s_waitcnt vmcnt(4)" ::: "memory");
    } else {
      asm volatile("s_waitcnt vmcnt(0)" ::: "memory");
    }
    TAIL28
    // rotations
    { int t0 = aC; aC = aN; aN = aS; aS = t0; }
    { int t1 = bC; bC = bO; bO = t1; }
    if ((kt & 3) == 3) { pc0 = pn0; pc1 = pn1; pc2 = pn2; pc3 = pn3; }
  }
#undef TAIL28
#undef MF
#undef LD
#undef SB
  asm volatile("s_waitcnt vmcnt(0)" ::: "memory");

  // ---- epilogue: bias + store (D: col = q, row = hi*4 + rr) ----
#pragma unroll
  for (int ni = 0; ni < 4; ++ni) {
    const int col = wn * 64 + ni * 16 + q;
#pragma unroll
    for (int mi = 0; mi < 7; ++mi) {
#pragma unroll
      for (int rr = 0; rr < 4; ++rr) {
        const int row = m0 + wm * 112 + mi * 16 + hi * 4 + rr;
        if (row < NF) out[row * 256 + col] = acc[mi][ni][rr] + bv[ni];
      }
    }
  }
}

extern "C" void kernel_launch(void* const* d_in, const int* in_sizes, int n_in,
                              void* d_out, int out_size, void* d_ws, size_t ws_size,
                              hipStream_t stream) {
  const float* x = (const float*)d_in[0];
  const float* wfull = (const float*)d_in[1];
  const float* bias = (const float*)d_in[2];
  const void* nbr = d_in[3];
  const unsigned char* pad = (const unsigned char*)d_in[4];
  float* out = (float*)d_out;
  char* ws = (char*)d_ws;

  unsigned short* wt   = (unsigned short*)(ws + WT_OFF);
  int* flag            = (int*)(ws + FLAG_OFF);
  int* cnt             = (int*)(ws + CNT_OFF);
  unsigned short* padx = (unsigned short*)(ws + PADX_OFF);

  k_prep<<<452, 256, 0, stream>>>(wfull, wt, pad, cnt, (const unsigned int*)nbr, flag);
  k_rankpadx<<<NCHUNK, 256, 0, stream>>>(x, pad, cnt, padx);
  k_main<<<NBLK3, 512, 0, stream>>>(padx, wt, nbr, flag, bias, out);
}

// Round 15
// 85.455 us; speedup vs baseline: 1.5503x; 1.0062x over previous
//
#include <hip/hip_runtime.h>

#define NF    50000
#define PADP  50001
#define KN    9
#define KTOT  2304
#define NCHUNK 782
#define BM3   224
#define NBLK3 224        // 224*224 = 50176 >= 50000; single round
#define NKT   36         // 2304/64 K-tiles
#define ABUF  28672      // one A buffer: 224 rows x 128B
#define BB    86016      // B dbuf base (2 x 32768)
#define IDXO  151552     // idx cache 224*9*4 = 8064 -> total 159616

// ---- ws layout (bytes) ----
#define WT_OFF   0u
#define FLAG_OFF 1179648u
#define CNT_OFF  1179904u
#define PADX_OFF 1183744u

typedef float f32x4 __attribute__((ext_vector_type(4)));
typedef __bf16 bf16x8 __attribute__((ext_vector_type(8)));

typedef const __attribute__((address_space(1))) unsigned int* gas_t;
typedef __attribute__((address_space(3))) unsigned int* las_t;

static __device__ __forceinline__ void gll16(const void* g, void* l) {
  __builtin_amdgcn_global_load_lds((gas_t)g, (las_t)l, 16, 0, 0);
}

static __device__ __forceinline__ unsigned short f2bf(float f) {
  unsigned int u = __builtin_bit_cast(unsigned int, f);
  u = u + 0x7fffu + ((u >> 16) & 1u);      // RNE
  return (unsigned short)(u >> 16);
}

// ---------- preprocessing (unchanged) ----------

__global__ void k_prep(const float* __restrict__ w, unsigned short* __restrict__ wt,
                       const unsigned char* __restrict__ pad, int* __restrict__ cnt,
                       const unsigned int* __restrict__ raw, int* __restrict__ flag) {
  if (blockIdx.x < 256) {
    int o = blockIdx.x;
    int i = threadIdx.x;
    const float* wr = w + (o * 256 + i) * 9;
    float wv[9];
    float s = 0.f;
#pragma unroll
    for (int k = 0; k < 9; ++k) { wv[k] = wr[k]; s += wv[k] * wv[k]; }
#pragma unroll
    for (int d = 32; d >= 1; d >>= 1) s += __shfl_xor(s, d);
    __shared__ float red[4];
    if ((i & 63) == 0) red[i >> 6] = s;
    __syncthreads();
    float dc = rsqrtf(red[0] + red[1] + red[2] + red[3] + 1e-8f);
#pragma unroll
    for (int k = 0; k < 9; ++k)
      wt[o * KTOT + k * 256 + i] = f2bf(wv[k] * dc);
  } else {
    int cb = blockIdx.x - 256;
    int t = cb * 256 + threadIdx.x;
    bool ip = (t < PADP) ? (pad[t] != 0) : true;
    unsigned long long m = __ballot(ip);
    int c = t >> 6;
    if ((threadIdx.x & 63) == 0 && c < NCHUNK) cnt[c] = __popcll(m);
    if (cb == 0 && threadIdx.x < 64) {
      unsigned int v = raw[threadIdx.x * 2 + 1];
      unsigned long long nz = __ballot(v != 0u);
      if (threadIdx.x == 0) flag[0] = (nz == 0ull) ? 1 : 0;
    }
  }
}

__global__ __launch_bounds__(256) void k_rankpadx(
    const float* __restrict__ x, const unsigned char* __restrict__ pad,
    const int* __restrict__ cnt, unsigned short* __restrict__ padx) {
  const int c = blockIdx.x;
  const int tid = threadIdx.x, w = tid >> 6, lane = tid & 63;
  int s = 0;
  for (int i = tid; i < c; i += 256) s += cnt[i];
#pragma unroll
  for (int d = 32; d >= 1; d >>= 1) s += __shfl_xor(s, d);
  __shared__ int red[4];
  __shared__ int rnk[64];
  if (lane == 0) red[w] = s;
  __syncthreads();
  const int S = red[0] + red[1] + red[2] + red[3];
  if (w == 0) {
    int p = c * 64 + lane;
    bool ip = (p < PADP) ? (pad[p] != 0) : true;
    unsigned long long m = __ballot(ip);
    int before = __popcll(m & ((1ull << lane) - 1ull));
    rnk[lane] = ip ? -1 : (p - (S + before));
  }
  __syncthreads();
  const int col = lane * 4;
#pragma unroll
  for (int i = 0; i < 16; ++i) {
    int rl = i * 4 + w;
    int pp = c * 64 + rl;
    if (pp >= PADP) continue;
    int rr = rnk[rl];
    ushort4 ov;
    if (rr < 0) { ov.x = 0; ov.y = 0; ov.z = 0; ov.w = 0; }
    else {
      const float4 v = *(const float4*)(x + rr * 256 + col);
      ov.x = f2bf(v.x); ov.y = f2bf(v.y); ov.z = f2bf(v.z); ov.w = f2bf(v.w);
    }
    *(ushort4*)(padx + pp * 256 + col) = ov;
  }
}

// ---------- main gathered GEMM: 1 barrier/K-tile, read/MFMA overlap ----------
// BM=224 x BN=256 x BK=64, 512 thr (8 waves 2M x 4N), wave-tile 112x64 (7x4).
// LDS: A ring-3 x 28KB + B dbuf 2 x 32KB + idx = 156KB. Grid 224.
// Per K-tile (ONE barrier):
//   [vmcnt(4) w0-6 / vmcnt(0) w7] barrier
//   issue 22 ds_reads (kk0 -> af/bq, kk1 -> af2/bq2; same buffers, no hazard)
//   issue stages: B(kt+1)->bO (all), A(kt+2)->aS (w0-6); idx refresh @kt%4==1
//   lgkmcnt(11) -> MFMA kk0 x28   (LDS pipe serves kk1 reads under MFMA)
//   lgkmcnt(0)  -> MFMA kk1 x28
// Hazards: next tile's stage targets drained by this tile's lgkmcnt(0) +
// next top barrier; vmcnt counts derived from per-class queues (see R15 notes).
__global__ __launch_bounds__(512, 1) void k_main(
    const unsigned short* __restrict__ padx,   // [50001][256] bf16
    const unsigned short* __restrict__ wt,     // [256][2304] bf16
    const void* __restrict__ nbr,              // [50000][9] int64 or int32
    const int* __restrict__ flag,
    const float* __restrict__ bias,            // [256]
    float* __restrict__ out) {                 // [50000][256] f32
  __shared__ __align__(16) unsigned char sm[159616];
  const int tid = threadIdx.x;
  const int wv = tid >> 6, lane = tid & 63;
  const int m0 = blockIdx.x * BM3;
  int* idxl = (int*)(sm + IDXO);

  const int q = lane & 15, hi = lane >> 4;
  const int wm = wv >> 2, wn = wv & 3;

  float bv[4];
#pragma unroll
  for (int ni = 0; ni < 4; ++ni) bv[ni] = bias[wn * 64 + ni * 16 + q];

  // idx cache: 224 rows x 9 neighbors (clamped faces)
  const bool f64 = (flag[0] != 0);
  const long long* n64 = (const long long*)nbr;
  const int* n32 = (const int*)nbr;
  for (int e = tid; e < BM3 * 9; e += 512) {
    int f = m0 + e / 9;
    if (f >= NF) f = NF - 1;
    int k = e - (e / 9) * 9;
    idxl[e] = f64 ? (int)n64[f * KN + k] : n32[f * KN + k];
  }
  __syncthreads();   // also drains bias vmem

  // ---- staging geometry ----
  const int swsrc = ((tid & 7) ^ ((tid >> 3) & 7)) * 8;
  const int dst16 = tid * 16;
  int rr0 = 0, rr1 = 0, rr2 = 0, rr3 = 0;
  if (tid < 448) {
    rr0 = (tid >> 3);
    rr1 = rr0 + 56; rr2 = rr0 + 112; rr3 = rr0 + 168;
  }
  const int fl0 = tid >> 3;
  const unsigned short* wtb00 = wt + (fl0      ) * KTOT + swsrc;
  const unsigned short* wtb01 = wt + (fl0 +  64) * KTOT + swsrc;
  const unsigned short* wtb10 = wt + (fl0 + 128) * KTOT + swsrc;
  const unsigned short* wtb11 = wt + (fl0 + 192) * KTOT + swsrc;

  // ---- fragment read offsets ----
  const int q7 = q & 7;
  const int s0 = ((hi    ) ^ q7) * 16;
  const int s1 = ((4 + hi) ^ q7) * 16;
  int aoffb[7], bofb[4];
#pragma unroll
  for (int mi = 0; mi < 7; ++mi) aoffb[mi] = (wm * 112 + mi * 16 + q) * 128;
#pragma unroll
  for (int ni = 0; ni < 4; ++ni) bofb[ni] = (wn * 64 + ni * 16 + q) * 128;

  f32x4 acc[7][4];
#pragma unroll
  for (int a = 0; a < 7; ++a)
#pragma unroll
    for (int b = 0; b < 4; ++b) {
      acc[a][b][0] = 0.f; acc[a][b][1] = 0.f; acc[a][b][2] = 0.f; acc[a][b][3] = 0.f;
    }

  int pc0 = 0, pc1 = 0, pc2 = 0, pc3 = 0, pn0 = 0, pn1 = 0, pn2 = 0, pn3 = 0;
  if (tid < 448) {
    pc0 = idxl[rr0 * 9]; pc1 = idxl[rr1 * 9]; pc2 = idxl[rr2 * 9]; pc3 = idxl[rr3 * 9];
    pn0 = pc0; pn1 = pc1; pn2 = pc2; pn3 = pc3;
  }

  // ---- prologue (queue order matters): A(0)->Ab0, B(0)->Bb0, A(1)->Ab1 ----
  if (tid < 448) {
    gll16(padx + pc0 * 256 +  0 + swsrc, sm + dst16);
    gll16(padx + pc1 * 256 +  0 + swsrc, sm + 7168 + dst16);
    gll16(padx + pc2 * 256 +  0 + swsrc, sm + 14336 + dst16);
    gll16(padx + pc3 * 256 +  0 + swsrc, sm + 21504 + dst16);
  }
  gll16(wtb00, sm + BB + dst16);
  gll16(wtb01, sm + BB + 8192 + dst16);
  gll16(wtb10, sm + BB + 16384 + dst16);
  gll16(wtb11, sm + BB + 24576 + dst16);
  if (tid < 448) {
    gll16(padx + pc0 * 256 + 64 + swsrc, sm + ABUF + dst16);
    gll16(padx + pc1 * 256 + 64 + swsrc, sm + ABUF + 7168 + dst16);
    gll16(padx + pc2 * 256 + 64 + swsrc, sm + ABUF + 14336 + dst16);
    gll16(padx + pc3 * 256 + 64 + swsrc, sm + ABUF + 21504 + dst16);
  }

  bf16x8 af[7], bq[4], af2[7], bq2[4];
  int aC = 0, aN = ABUF, aS = 2 * ABUF;
  int bC = BB, bO = BB + 32768;

#define LD(p) (*(const bf16x8*)(p))
#define SB __builtin_amdgcn_sched_barrier(0);
#define MF(MI, AF, BQ) \
  acc[MI][0] = __builtin_amdgcn_mfma_f32_16x16x32_bf16(AF[MI], BQ[0], acc[MI][0], 0,0,0); \
  acc[MI][1] = __builtin_amdgcn_mfma_f32_16x16x32_bf16(AF[MI], BQ[1], acc[MI][1], 0,0,0); \
  acc[MI][2] = __builtin_amdgcn_mfma_f32_16x16x32_bf16(AF[MI], BQ[2], acc[MI][2], 0,0,0); \
  acc[MI][3] = __builtin_amdgcn_mfma_f32_16x16x32_bf16(AF[MI], BQ[3], acc[MI][3], 0,0,0);

#pragma unroll 1
  for (int kt = 0; kt < NKT; ++kt) {
    // ---- top: residency + the ONLY barrier ----
    if (tid < 448) asm volatile("s_waitcnt vmcnt(4)" ::: "memory");
    else           asm volatile("s_waitcnt vmcnt(0)" ::: "memory");
    SB
    __builtin_amdgcn_s_barrier();
    SB
    // ---- issue all 22 ds_reads (kk0 then kk1) ----
#pragma unroll
    for (int mi = 0; mi < 7; ++mi) af[mi] = LD(sm + aC + aoffb[mi] + s0);
#pragma unroll
    for (int ni = 0; ni < 4; ++ni) bq[ni] = LD(sm + bC + bofb[ni] + s0);
#pragma unroll
    for (int mi = 0; mi < 7; ++mi) af2[mi] = LD(sm + aC + aoffb[mi] + s1);
#pragma unroll
    for (int ni = 0; ni < 4; ++ni) bq2[ni] = LD(sm + bC + bofb[ni] + s1);
    SB
    // ---- issue stages: B(kt+1)->bO (all), A(kt+2)->aS (w0-6) ----
    {
      const int kb = ((kt + 1 < NKT) ? kt + 1 : NKT - 1) * 64;
      gll16(wtb00 + kb, sm + bO + dst16);
      gll16(wtb01 + kb, sm + bO + 8192 + dst16);
      gll16(wtb10 + kb, sm + bO + 16384 + dst16);
      gll16(wtb11 + kb, sm + bO + 24576 + dst16);
    }
    if (tid < 448) {
      const int c0 = ((kt + 2) & 3) * 64;
      const int u0 = ((kt & 3) < 2) ? pc0 : pn0;
      const int u1 = ((kt & 3) < 2) ? pc1 : pn1;
      const int u2 = ((kt & 3) < 2) ? pc2 : pn2;
      const int u3 = ((kt & 3) < 2) ? pc3 : pn3;
      gll16(padx + u0 * 256 + c0 + swsrc, sm + aS + dst16);
      gll16(padx + u1 * 256 + c0 + swsrc, sm + aS + 7168 + dst16);
      gll16(padx + u2 * 256 + c0 + swsrc, sm + aS + 14336 + dst16);
      gll16(padx + u3 * 256 + c0 + swsrc, sm + aS + 21504 + dst16);
    }
    if ((kt & 3) == 1 && tid < 448) {
      int gn = (kt >> 2) + 1; if (gn > 8) gn = 8;
      pn0 = idxl[rr0 * 9 + gn]; pn1 = idxl[rr1 * 9 + gn];
      pn2 = idxl[rr2 * 9 + gn]; pn3 = idxl[rr3 * 9 + gn];
    }
    SB
    // ---- kk0 ready -> MFMA kk0 (LDS pipe serves kk1 under it) ----
    asm volatile("s_waitcnt lgkmcnt(11)" ::: "memory");
    SB
    __builtin_amdgcn_s_setprio(1);
    MF(0, af, bq) MF(1, af, bq) MF(2, af, bq) MF(3, af, bq)
    MF(4, af, bq) MF(5, af, bq) MF(6, af, bq)
    __builtin_amdgcn_s_setprio(0);
    SB
    // ---- kk1 ready -> MFMA kk1 ----
    asm volatile("s_waitcnt lgkmcnt(0)" ::: "memory");
    SB
    __builtin_amdgcn_s_setprio(1);
    MF(0, af2, bq2) MF(1, af2, bq2) MF(2, af2, bq2) MF(3, af2, bq2)
    MF(4, af2, bq2) MF(5, af2, bq2) MF(6, af2, bq2)
    __builtin_amdgcn_s_setprio(0);
    SB
    // ---- rotations ----
    { int t0 = aC; aC = aN; aN = aS; aS = t0; }
    { int t1 = bC; bC = bO; bO = t1; }
    if ((kt & 3) == 3) { pc0 = pn0; pc1 = pn1; pc2 = pn2; pc3 = pn3; }
  }
#undef MF
#undef LD
#undef SB
  asm volatile("s_waitcnt vmcnt(0)" ::: "memory");

  // ---- epilogue: bias + store (D: col = q, row = hi*4 + rr) ----
#pragma unroll
  for (int ni = 0; ni < 4; ++ni) {
    const int col = wn * 64 + ni * 16 + q;
#pragma unroll
    for (int mi = 0; mi < 7; ++mi) {
#pragma unroll
      for (int rr = 0; rr < 4; ++rr) {
        const int row = m0 + wm * 112 + mi * 16 + hi * 4 + rr;
        if (row < NF) out[row * 256 + col] = acc[mi][ni][rr] + bv[ni];
      }
    }
  }
}

extern "C" void kernel_launch(void* const* d_in, const int* in_sizes, int n_in,
                              void* d_out, int out_size, void* d_ws, size_t ws_size,
                              hipStream_t stream) {
  const float* x = (const float*)d_in[0];
  const float* wfull = (const float*)d_in[1];
  const float* bias = (const float*)d_in[2];
  const void* nbr = d_in[3];
  const unsigned char* pad = (const unsigned char*)d_in[4];
  float* out = (float*)d_out;
  char* ws = (char*)d_ws;

  unsigned short* wt   = (unsigned short*)(ws + WT_OFF);
  int* flag            = (int*)(ws + FLAG_OFF);
  int* cnt             = (int*)(ws + CNT_OFF);
  unsigned short* padx = (unsigned short*)(ws + PADX_OFF);

  k_prep<<<452, 256, 0, stream>>>(wfull, wt, pad, cnt, (const unsigned int*)nbr, flag);
  k_rankpadx<<<NCHUNK, 256, 0, stream>>>(x, pad, cnt, padx);
  k_main<<<NBLK3, 512, 0, stream>>>(padx, wt, nbr, flag, bias, out);
}

// Round 16
// 85.352 us; speedup vs baseline: 1.5521x; 1.0012x over previous
//
#include <hip/hip_runtime.h>

#define NF    50000
#define PADP  50001
#define KN    9
#define KTOT  2304
#define NCHUNK 782
#define BM3   224
#define NBLK3 224        // single round on 256 CUs
#define NKT   36         // 2304/64 K-tiles
#define ABUF  28672      // one A buffer: 224 rows x 128B
#define BB    86016      // B dbuf base (2 x 32768)
#define IDXO  151552     // ushort idx cache 224*9*2 = 4032 -> total 155584

// ---- ws layout (bytes) ----
#define WT_OFF   0u
#define FLAG_OFF 1179648u
#define CNT_OFF  1179904u
#define PADX_OFF 1183744u

typedef float f32x4 __attribute__((ext_vector_type(4)));
typedef __bf16 bf16x8 __attribute__((ext_vector_type(8)));

typedef const __attribute__((address_space(1))) unsigned int* gas_t;
typedef __attribute__((address_space(3))) unsigned int* las_t;

static __device__ __forceinline__ void gll16(const void* g, void* l) {
  __builtin_amdgcn_global_load_lds((gas_t)g, (las_t)l, 16, 0, 0);
}

static __device__ __forceinline__ unsigned short f2bf(float f) {
  unsigned int u = __builtin_bit_cast(unsigned int, f);
  u = u + 0x7fffu + ((u >> 16) & 1u);      // RNE
  return (unsigned short)(u >> 16);
}

// ---------- preprocessing (unchanged) ----------

__global__ void k_prep(const float* __restrict__ w, unsigned short* __restrict__ wt,
                       const unsigned char* __restrict__ pad, int* __restrict__ cnt,
                       const unsigned int* __restrict__ raw, int* __restrict__ flag) {
  if (blockIdx.x < 256) {
    int o = blockIdx.x;
    int i = threadIdx.x;
    const float* wr = w + (o * 256 + i) * 9;
    float wv[9];
    float s = 0.f;
#pragma unroll
    for (int k = 0; k < 9; ++k) { wv[k] = wr[k]; s += wv[k] * wv[k]; }
#pragma unroll
    for (int d = 32; d >= 1; d >>= 1) s += __shfl_xor(s, d);
    __shared__ float red[4];
    if ((i & 63) == 0) red[i >> 6] = s;
    __syncthreads();
    float dc = rsqrtf(red[0] + red[1] + red[2] + red[3] + 1e-8f);
#pragma unroll
    for (int k = 0; k < 9; ++k)
      wt[o * KTOT + k * 256 + i] = f2bf(wv[k] * dc);
  } else {
    int cb = blockIdx.x - 256;
    int t = cb * 256 + threadIdx.x;
    bool ip = (t < PADP) ? (pad[t] != 0) : true;
    unsigned long long m = __ballot(ip);
    int c = t >> 6;
    if ((threadIdx.x & 63) == 0 && c < NCHUNK) cnt[c] = __popcll(m);
    if (cb == 0 && threadIdx.x < 64) {
      unsigned int v = raw[threadIdx.x * 2 + 1];
      unsigned long long nz = __ballot(v != 0u);
      if (threadIdx.x == 0) flag[0] = (nz == 0ull) ? 1 : 0;
    }
  }
}

__global__ __launch_bounds__(256) void k_rankpadx(
    const float* __restrict__ x, const unsigned char* __restrict__ pad,
    const int* __restrict__ cnt, unsigned short* __restrict__ padx) {
  const int c = blockIdx.x;
  const int tid = threadIdx.x, w = tid >> 6, lane = tid & 63;
  int s = 0;
  for (int i = tid; i < c; i += 256) s += cnt[i];
#pragma unroll
  for (int d = 32; d >= 1; d >>= 1) s += __shfl_xor(s, d);
  __shared__ int red[4];
  __shared__ int rnk[64];
  if (lane == 0) red[w] = s;
  __syncthreads();
  const int S = red[0] + red[1] + red[2] + red[3];
  if (w == 0) {
    int p = c * 64 + lane;
    bool ip = (p < PADP) ? (pad[p] != 0) : true;
    unsigned long long m = __ballot(ip);
    int before = __popcll(m & ((1ull << lane) - 1ull));
    rnk[lane] = ip ? -1 : (p - (S + before));
  }
  __syncthreads();
  const int col = lane * 4;
#pragma unroll
  for (int i = 0; i < 16; ++i) {
    int rl = i * 4 + w;
    int pp = c * 64 + rl;
    if (pp >= PADP) continue;
    int rr = rnk[rl];
    ushort4 ov;
    if (rr < 0) { ov.x = 0; ov.y = 0; ov.z = 0; ov.w = 0; }
    else {
      const float4 v = *(const float4*)(x + rr * 256 + col);
      ov.x = f2bf(v.x); ov.y = f2bf(v.y); ov.z = f2bf(v.z); ov.w = f2bf(v.w);
    }
    *(ushort4*)(padx + pp * 256 + col) = ov;
  }
}

// ---------- main gathered GEMM: 16 waves (4/SIMD), 1 barrier/K-tile ----------
// BM=224 x BN=256 x BK=64, 1024 thr (16 waves, 2M x 8N), wave-tile 112x32
// (acc 7x2 = 56 VGPR -> fits the 128-VGPR cap 4 waves/SIMD needs).
// LDS: A ring-3 x 28KB + B dbuf 2 x 32KB + ushort idx 4KB = 152KB. Grid 224.
// Per K-tile (ONE barrier):
//   [vmcnt(2) w0-13 / vmcnt(0) w14-15]  barrier
//   stage B(kt+1)->bO (2 gll16, all thr); stage A(kt+2)->aS (2 gll16, w0-13)
//   per kk in {0,1}: 7A+2B ds_reads -> setprio(1) 14 MFMA setprio(0)
//   (compiler schedules fine-grained lgkmcnt; 4 waves/SIMD cover the waits)
// vmcnt derivation (w0-13 queue at top): [A(kt),B(kt),A(kt+1)] 6 outstanding
//   -> vmcnt(2) drains A(kt),B(kt), leaves A(kt+1)x2. A flight = 2 K-tiles.
__global__ __launch_bounds__(1024, 1) void k_main(
    const unsigned short* __restrict__ padx,   // [50001][256] bf16
    const unsigned short* __restrict__ wt,     // [256][2304] bf16
    const void* __restrict__ nbr,              // [50000][9] int64 or int32
    const int* __restrict__ flag,
    const float* __restrict__ bias,            // [256]
    float* __restrict__ out) {                 // [50000][256] f32
  __shared__ __align__(16) unsigned char sm[155584];
  const int tid = threadIdx.x;
  const int wv = tid >> 6, lane = tid & 63;
  const int m0 = blockIdx.x * BM3;
  unsigned short* idxl = (unsigned short*)(sm + IDXO);

  const int q = lane & 15, hi = lane >> 4;
  const int wm = wv >> 3, wn = wv & 7;

  float bv[2];
#pragma unroll
  for (int ni = 0; ni < 2; ++ni) bv[ni] = bias[wn * 32 + ni * 16 + q];

  // ushort idx cache: 224 rows x 9 neighbors (clamped faces; values < 50001)
  const bool f64 = (flag[0] != 0);
  const long long* n64 = (const long long*)nbr;
  const int* n32 = (const int*)nbr;
  for (int e = tid; e < BM3 * 9; e += 1024) {
    int f = m0 + e / 9;
    if (f >= NF) f = NF - 1;
    int k = e - (e / 9) * 9;
    idxl[e] = (unsigned short)(f64 ? (int)n64[f * KN + k] : n32[f * KN + k]);
  }
  __syncthreads();   // drains bias/idx vmem -> clean queue

  // ---- staging geometry ----
  const int swsrc = ((tid & 7) ^ ((tid >> 3) & 7)) * 8;
  const int dst16 = tid * 16;
  const int r0 = tid >> 3;                 // A rows (w0-13): r0 (0..111), r0+112
  const unsigned short* wtb0 = wt + (tid >> 3) * KTOT + swsrc;          // B rows 0..127
  const unsigned short* wtb1 = wt + (128 + (tid >> 3)) * KTOT + swsrc;  // 128..255

  // ---- fragment read offsets ----
  const int q7 = q & 7;
  const int s0 = ((hi    ) ^ q7) * 16;
  const int s1 = ((4 + hi) ^ q7) * 16;
  int aoffb[7], bofb[2];
#pragma unroll
  for (int mi = 0; mi < 7; ++mi) aoffb[mi] = (wm * 112 + mi * 16 + q) * 128;
#pragma unroll
  for (int ni = 0; ni < 2; ++ni) bofb[ni] = (wn * 32 + ni * 16 + q) * 128;

  f32x4 acc[7][2];
#pragma unroll
  for (int a = 0; a < 7; ++a)
#pragma unroll
    for (int b = 0; b < 2; ++b) {
      acc[a][b][0] = 0.f; acc[a][b][1] = 0.f; acc[a][b][2] = 0.f; acc[a][b][3] = 0.f;
    }

  int pc0 = 0, pc1 = 0, pn0 = 0, pn1 = 0;
  if (wv < 14) {
    pc0 = idxl[r0 * 9]; pc1 = idxl[(r0 + 112) * 9];
    pn0 = pc0; pn1 = pc1;
  }

  // ---- prologue (queue order: A(0), B(0), A(1)) ----
  if (wv < 14) {
    gll16(padx + pc0 * 256 +  0 + swsrc, sm + dst16);
    gll16(padx + pc1 * 256 +  0 + swsrc, sm + 14336 + dst16);
  }
  gll16(wtb0, sm + BB + dst16);
  gll16(wtb1, sm + BB + 16384 + dst16);
  if (wv < 14) {
    gll16(padx + pc0 * 256 + 64 + swsrc, sm + ABUF + dst16);
    gll16(padx + pc1 * 256 + 64 + swsrc, sm + ABUF + 14336 + dst16);
  }

  bf16x8 af[7], bq[2];
  int aC = 0, aN = ABUF, aS = 2 * ABUF;
  int bC = BB, bO = BB + 32768;

#define LD(p) (*(const bf16x8*)(p))
#define SB __builtin_amdgcn_sched_barrier(0);
#define MF(MI, S) \
  acc[MI][0] = __builtin_amdgcn_mfma_f32_16x16x32_bf16(af[MI], bq[0], acc[MI][0], 0,0,0); \
  acc[MI][1] = __builtin_amdgcn_mfma_f32_16x16x32_bf16(af[MI], bq[1], acc[MI][1], 0,0,0);

#pragma unroll 1
  for (int kt = 0; kt < NKT; ++kt) {
    // ---- top: residency + the ONLY barrier ----
    if (wv < 14) asm volatile("s_waitcnt vmcnt(2)" ::: "memory");
    else         asm volatile("s_waitcnt vmcnt(0)" ::: "memory");
    SB
    __builtin_amdgcn_s_barrier();
    SB
    // ---- stages: B(kt+1)->bO (all), then A(kt+2)->aS (w0-13) ----
    {
      const int kb = ((kt + 1 < NKT) ? kt + 1 : NKT - 1) * 64;
      gll16(wtb0 + kb, sm + bO + dst16);
      gll16(wtb1 + kb, sm + bO + 16384 + dst16);
    }
    SB
    if (wv < 14) {
      const int c0 = ((kt + 2) & 3) * 64;
      const int u0 = ((kt & 3) < 2) ? pc0 : pn0;
      const int u1 = ((kt & 3) < 2) ? pc1 : pn1;
      gll16(padx + u0 * 256 + c0 + swsrc, sm + aS + dst16);
      gll16(padx + u1 * 256 + c0 + swsrc, sm + aS + 14336 + dst16);
    }
    if ((kt & 3) == 1 && wv < 14) {
      int gn = (kt >> 2) + 1; if (gn > 8) gn = 8;
      pn0 = idxl[r0 * 9 + gn]; pn1 = idxl[(r0 + 112) * 9 + gn];
    }
    SB
    // ---- kk0: 9 ds_reads + 14 MFMA ----
#pragma unroll
    for (int mi = 0; mi < 7; ++mi) af[mi] = LD(sm + aC + aoffb[mi] + s0);
    bq[0] = LD(sm + bC + bofb[0] + s0);
    bq[1] = LD(sm + bC + bofb[1] + s0);
    __builtin_amdgcn_s_setprio(1);
    MF(0,0) MF(1,0) MF(2,0) MF(3,0) MF(4,0) MF(5,0) MF(6,0)
    __builtin_amdgcn_s_setprio(0);
    // ---- kk1: 9 ds_reads + 14 MFMA ----
#pragma unroll
    for (int mi = 0; mi < 7; ++mi) af[mi] = LD(sm + aC + aoffb[mi] + s1);
    bq[0] = LD(sm + bC + bofb[0] + s1);
    bq[1] = LD(sm + bC + bofb[1] + s1);
    __builtin_amdgcn_s_setprio(1);
    MF(0,1) MF(1,1) MF(2,1) MF(3,1) MF(4,1) MF(5,1) MF(6,1)
    __builtin_amdgcn_s_setprio(0);
    SB
    // ---- rotations ----
    { int t0 = aC; aC = aN; aN = aS; aS = t0; }
    { int t1 = bC; bC = bO; bO = t1; }
    if ((kt & 3) == 3) { pc0 = pn0; pc1 = pn1; }
  }
#undef MF
#undef LD
#undef SB
  asm volatile("s_waitcnt vmcnt(0)" ::: "memory");

  // ---- epilogue: bias + store (D: col = q, row = hi*4 + rr) ----
#pragma unroll
  for (int ni = 0; ni < 2; ++ni) {
    const int col = wn * 32 + ni * 16 + q;
#pragma unroll
    for (int mi = 0; mi < 7; ++mi) {
#pragma unroll
      for (int rr = 0; rr < 4; ++rr) {
        const int row = m0 + wm * 112 + mi * 16 + hi * 4 + rr;
        if (row < NF) out[row * 256 + col] = acc[mi][ni][rr] + bv[ni];
      }
    }
  }
}

extern "C" void kernel_launch(void* const* d_in, const int* in_sizes, int n_in,
                              void* d_out, int out_size, void* d_ws, size_t ws_size,
                              hipStream_t stream) {
  const float* x = (const float*)d_in[0];
  const float* wfull = (const float*)d_in[1];
  const float* bias = (const float*)d_in[2];
  const void* nbr = d_in[3];
  const unsigned char* pad = (const unsigned char*)d_in[4];
  float* out = (float*)d_out;
  char* ws = (char*)d_ws;

  unsigned short* wt   = (unsigned short*)(ws + WT_OFF);
  int* flag            = (int*)(ws + FLAG_OFF);
  int* cnt             = (int*)(ws + CNT_OFF);
  unsigned short* padx = (unsigned short*)(ws + PADX_OFF);

  k_prep<<<452, 256, 0, stream>>>(wfull, wt, pad, cnt, (const unsigned int*)nbr, flag);
  k_rankpadx<<<NCHUNK, 256, 0, stream>>>(x, pad, cnt, padx);
  k_main<<<NBLK3, 1024, 0, stream>>>(padx, wt, nbr, flag, bias, out);
}

// Round 17
// 84.960 us; speedup vs baseline: 1.5593x; 1.0046x over previous
//
#include <hip/hip_runtime.h>

#define NF    50000
#define PADP  50001
#define KN    9
#define KTOT  2304
#define NCHUNK 782
#define BM3   224
#define NBLK3 224        // single round on 256 CUs
#define NKT   36         // 2304/64 K-tiles
#define ABUF  28672      // one A buffer: 224 rows x 128B
#define BB    86016      // B dbuf base (2 x 32768)
#define IDXO  151552     // ushort idx cache 224*9*2 = 4032 -> total 155584

// ---- ws layout (bytes) ----
#define WT_OFF   0u
#define FLAG_OFF 1179648u
#define CNT_OFF  1179904u
#define PADX_OFF 1183744u

typedef float f32x4 __attribute__((ext_vector_type(4)));
typedef __bf16 bf16x8 __attribute__((ext_vector_type(8)));

typedef const __attribute__((address_space(1))) unsigned int* gas_t;
typedef __attribute__((address_space(3))) unsigned int* las_t;

static __device__ __forceinline__ void gll16(const void* g, void* l) {
  __builtin_amdgcn_global_load_lds((gas_t)g, (las_t)l, 16, 0, 0);
}

static __device__ __forceinline__ unsigned short f2bf(float f) {
  unsigned int u = __builtin_bit_cast(unsigned int, f);
  u = u + 0x7fffu + ((u >> 16) & 1u);      // RNE
  return (unsigned short)(u >> 16);
}

// ---------- preprocessing (unchanged) ----------

__global__ void k_prep(const float* __restrict__ w, unsigned short* __restrict__ wt,
                       const unsigned char* __restrict__ pad, int* __restrict__ cnt,
                       const unsigned int* __restrict__ raw, int* __restrict__ flag) {
  if (blockIdx.x < 256) {
    int o = blockIdx.x;
    int i = threadIdx.x;
    const float* wr = w + (o * 256 + i) * 9;
    float wv[9];
    float s = 0.f;
#pragma unroll
    for (int k = 0; k < 9; ++k) { wv[k] = wr[k]; s += wv[k] * wv[k]; }
#pragma unroll
    for (int d = 32; d >= 1; d >>= 1) s += __shfl_xor(s, d);
    __shared__ float red[4];
    if ((i & 63) == 0) red[i >> 6] = s;
    __syncthreads();
    float dc = rsqrtf(red[0] + red[1] + red[2] + red[3] + 1e-8f);
#pragma unroll
    for (int k = 0; k < 9; ++k)
      wt[o * KTOT + k * 256 + i] = f2bf(wv[k] * dc);
  } else {
    int cb = blockIdx.x - 256;
    int t = cb * 256 + threadIdx.x;
    bool ip = (t < PADP) ? (pad[t] != 0) : true;
    unsigned long long m = __ballot(ip);
    int c = t >> 6;
    if ((threadIdx.x & 63) == 0 && c < NCHUNK) cnt[c] = __popcll(m);
    if (cb == 0 && threadIdx.x < 64) {
      unsigned int v = raw[threadIdx.x * 2 + 1];
      unsigned long long nz = __ballot(v != 0u);
      if (threadIdx.x == 0) flag[0] = (nz == 0ull) ? 1 : 0;
    }
  }
}

__global__ __launch_bounds__(256) void k_rankpadx(
    const float* __restrict__ x, const unsigned char* __restrict__ pad,
    const int* __restrict__ cnt, unsigned short* __restrict__ padx) {
  const int c = blockIdx.x;
  const int tid = threadIdx.x, w = tid >> 6, lane = tid & 63;
  int s = 0;
  for (int i = tid; i < c; i += 256) s += cnt[i];
#pragma unroll
  for (int d = 32; d >= 1; d >>= 1) s += __shfl_xor(s, d);
  __shared__ int red[4];
  __shared__ int rnk[64];
  if (lane == 0) red[w] = s;
  __syncthreads();
  const int S = red[0] + red[1] + red[2] + red[3];
  if (w == 0) {
    int p = c * 64 + lane;
    bool ip = (p < PADP) ? (pad[p] != 0) : true;
    unsigned long long m = __ballot(ip);
    int before = __popcll(m & ((1ull << lane) - 1ull));
    rnk[lane] = ip ? -1 : (p - (S + before));
  }
  __syncthreads();
  const int col = lane * 4;
#pragma unroll
  for (int i = 0; i < 16; ++i) {
    int rl = i * 4 + w;
    int pp = c * 64 + rl;
    if (pp >= PADP) continue;
    int rr = rnk[rl];
    ushort4 ov;
    if (rr < 0) { ov.x = 0; ov.y = 0; ov.z = 0; ov.w = 0; }
    else {
      const float4 v = *(const float4*)(x + rr * 256 + col);
      ov.x = f2bf(v.x); ov.y = f2bf(v.y); ov.z = f2bf(v.z); ov.w = f2bf(v.w);
    }
    *(ushort4*)(padx + pp * 256 + col) = ov;
  }
}

// ---------- main gathered GEMM: 16 waves, wave-parity staggered kk ----------
// BM=224 x BN=256 x BK=64, 1024 thr (16 waves, 2M x 8N), wave-tile 112x32.
// LDS: A ring-3 x 28KB + B dbuf 2 x 32KB + ushort idx 4KB = 152KB. Grid 224.
// Per K-tile (ONE barrier), with 2-COLOR WAVE STAGGER:
//   even waves: read kk0 -> MFMA kk0 -> read kk1 -> MFMA kk1
//   odd  waves: read kk1 -> MFMA kk1 -> read kk0 -> MFMA kk0
// At any instant ~half the waves feed the LDS pipe while half feed the MFMA
// pipe (pipes are separate, m114) -> ceiling max(MFMA,LDS) not sum.
// setprio(1) around MFMA now has a real role-split to arbitrate (T5 gate).
// Separate frag regs (af2/bq2) for the 2nd kk remove the WAR serialization.
__global__ __launch_bounds__(1024, 1) void k_main(
    const unsigned short* __restrict__ padx,   // [50001][256] bf16
    const unsigned short* __restrict__ wt,     // [256][2304] bf16
    const void* __restrict__ nbr,              // [50000][9] int64 or int32
    const int* __restrict__ flag,
    const float* __restrict__ bias,            // [256]
    float* __restrict__ out) {                 // [50000][256] f32
  __shared__ __align__(16) unsigned char sm[155584];
  const int tid = threadIdx.x;
  const int wv = tid >> 6, lane = tid & 63;
  const int m0 = blockIdx.x * BM3;
  unsigned short* idxl = (unsigned short*)(sm + IDXO);

  const int q = lane & 15, hi = lane >> 4;
  const int wm = wv >> 3, wn = wv & 7;

  float bv[2];
#pragma unroll
  for (int ni = 0; ni < 2; ++ni) bv[ni] = bias[wn * 32 + ni * 16 + q];

  // ushort idx cache: 224 rows x 9 neighbors (clamped faces; values < 50001)
  const bool f64 = (flag[0] != 0);
  const long long* n64 = (const long long*)nbr;
  const int* n32 = (const int*)nbr;
  for (int e = tid; e < BM3 * 9; e += 1024) {
    int f = m0 + e / 9;
    if (f >= NF) f = NF - 1;
    int k = e - (e / 9) * 9;
    idxl[e] = (unsigned short)(f64 ? (int)n64[f * KN + k] : n32[f * KN + k]);
  }
  __syncthreads();   // drains bias/idx vmem -> clean queue

  // ---- staging geometry ----
  const int swsrc = ((tid & 7) ^ ((tid >> 3) & 7)) * 8;
  const int dst16 = tid * 16;
  const int r0 = tid >> 3;                 // A rows (w0-13): r0 (0..111), r0+112
  const unsigned short* wtb0 = wt + (tid >> 3) * KTOT + swsrc;          // B rows 0..127
  const unsigned short* wtb1 = wt + (128 + (tid >> 3)) * KTOT + swsrc;  // 128..255

  // ---- fragment read offsets; parity picks kk order ----
  const int q7 = q & 7;
  const int sl0 = ((hi    ) ^ q7) * 16;    // kk=0 slot
  const int sl1 = ((4 + hi) ^ q7) * 16;    // kk=1 slot
  const int par = wv & 1;
  const int sA = par ? sl1 : sl0;          // first-processed kk slot
  const int sB = par ? sl0 : sl1;          // second-processed kk slot
  int aoffb[7], bofb[2];
#pragma unroll
  for (int mi = 0; mi < 7; ++mi) aoffb[mi] = (wm * 112 + mi * 16 + q) * 128;
#pragma unroll
  for (int ni = 0; ni < 2; ++ni) bofb[ni] = (wn * 32 + ni * 16 + q) * 128;

  f32x4 acc[7][2];
#pragma unroll
  for (int a = 0; a < 7; ++a)
#pragma unroll
    for (int b = 0; b < 2; ++b) {
      acc[a][b][0] = 0.f; acc[a][b][1] = 0.f; acc[a][b][2] = 0.f; acc[a][b][3] = 0.f;
    }

  int pc0 = 0, pc1 = 0, pn0 = 0, pn1 = 0;
  if (wv < 14) {
    pc0 = idxl[r0 * 9]; pc1 = idxl[(r0 + 112) * 9];
    pn0 = pc0; pn1 = pc1;
  }

  // ---- prologue (queue order: A(0), B(0), A(1)) ----
  if (wv < 14) {
    gll16(padx + pc0 * 256 +  0 + swsrc, sm + dst16);
    gll16(padx + pc1 * 256 +  0 + swsrc, sm + 14336 + dst16);
  }
  gll16(wtb0, sm + BB + dst16);
  gll16(wtb1, sm + BB + 16384 + dst16);
  if (wv < 14) {
    gll16(padx + pc0 * 256 + 64 + swsrc, sm + ABUF + dst16);
    gll16(padx + pc1 * 256 + 64 + swsrc, sm + ABUF + 14336 + dst16);
  }

  bf16x8 af[7], bq[2], af2[7], bq2[2];
  int aC = 0, aN = ABUF, aS = 2 * ABUF;
  int bC = BB, bO = BB + 32768;

#define LD(p) (*(const bf16x8*)(p))
#define SB __builtin_amdgcn_sched_barrier(0);
#define MFA(MI) \
  acc[MI][0] = __builtin_amdgcn_mfma_f32_16x16x32_bf16(af[MI], bq[0], acc[MI][0], 0,0,0); \
  acc[MI][1] = __builtin_amdgcn_mfma_f32_16x16x32_bf16(af[MI], bq[1], acc[MI][1], 0,0,0);
#define MFB(MI) \
  acc[MI][0] = __builtin_amdgcn_mfma_f32_16x16x32_bf16(af2[MI], bq2[0], acc[MI][0], 0,0,0); \
  acc[MI][1] = __builtin_amdgcn_mfma_f32_16x16x32_bf16(af2[MI], bq2[1], acc[MI][1], 0,0,0);

#pragma unroll 1
  for (int kt = 0; kt < NKT; ++kt) {
    // ---- top: residency + the ONLY barrier ----
    if (wv < 14) asm volatile("s_waitcnt vmcnt(2)" ::: "memory");
    else         asm volatile("s_waitcnt vmcnt(0)" ::: "memory");
    SB
    __builtin_amdgcn_s_barrier();
    SB
    // ---- stages: B(kt+1)->bO (all), then A(kt+2)->aS (w0-13) ----
    {
      const int kb = ((kt + 1 < NKT) ? kt + 1 : NKT - 1) * 64;
      gll16(wtb0 + kb, sm + bO + dst16);
      gll16(wtb1 + kb, sm + bO + 16384 + dst16);
    }
    SB
    if (wv < 14) {
      const int c0 = ((kt + 2) & 3) * 64;
      const int u0 = ((kt & 3) < 2) ? pc0 : pn0;
      const int u1 = ((kt & 3) < 2) ? pc1 : pn1;
      gll16(padx + u0 * 256 + c0 + swsrc, sm + aS + dst16);
      gll16(padx + u1 * 256 + c0 + swsrc, sm + aS + 14336 + dst16);
    }
    if ((kt & 3) == 1 && wv < 14) {
      int gn = (kt >> 2) + 1; if (gn > 8) gn = 8;
      pn0 = idxl[r0 * 9 + gn]; pn1 = idxl[(r0 + 112) * 9 + gn];
    }
    SB
    // ---- first kk (parity-selected): 9 ds_reads + 14 MFMA ----
#pragma unroll
    for (int mi = 0; mi < 7; ++mi) af[mi] = LD(sm + aC + aoffb[mi] + sA);
    bq[0] = LD(sm + bC + bofb[0] + sA);
    bq[1] = LD(sm + bC + bofb[1] + sA);
    __builtin_amdgcn_s_setprio(1);
    MFA(0) MFA(1) MFA(2) MFA(3) MFA(4) MFA(5) MFA(6)
    __builtin_amdgcn_s_setprio(0);
    // ---- second kk: 9 ds_reads + 14 MFMA (separate regs: no WAR stall) ----
#pragma unroll
    for (int mi = 0; mi < 7; ++mi) af2[mi] = LD(sm + aC + aoffb[mi] + sB);
    bq2[0] = LD(sm + bC + bofb[0] + sB);
    bq2[1] = LD(sm + bC + bofb[1] + sB);
    __builtin_amdgcn_s_setprio(1);
    MFB(0) MFB(1) MFB(2) MFB(3) MFB(4) MFB(5) MFB(6)
    __builtin_amdgcn_s_setprio(0);
    SB
    // ---- rotations ----
    { int t0 = aC; aC = aN; aN = aS; aS = t0; }
    { int t1 = bC; bC = bO; bO = t1; }
    if ((kt & 3) == 3) { pc0 = pn0; pc1 = pn1; }
  }
#undef MFA
#undef MFB
#undef LD
#undef SB
  asm volatile("s_waitcnt vmcnt(0)" ::: "memory");

  // ---- epilogue: bias + store (D: col = q, row = hi*4 + rr) ----
#pragma unroll
  for (int ni = 0; ni < 2; ++ni) {
    const int col = wn * 32 + ni * 16 + q;
#pragma unroll
    for (int mi = 0; mi < 7; ++mi) {
#pragma unroll
      for (int rr = 0; rr < 4; ++rr) {
        const int row = m0 + wm * 112 + mi * 16 + hi * 4 + rr;
        if (row < NF) out[row * 256 + col] = acc[mi][ni][rr] + bv[ni];
      }
    }
  }
}

extern "C" void kernel_launch(void* const* d_in, const int* in_sizes, int n_in,
                              void* d_out, int out_size, void* d_ws, size_t ws_size,
                              hipStream_t stream) {
  const float* x = (const float*)d_in[0];
  const float* wfull = (const float*)d_in[1];
  const float* bias = (const float*)d_in[2];
  const void* nbr = d_in[3];
  const unsigned char* pad = (const unsigned char*)d_in[4];
  float* out = (float*)d_out;
  char* ws = (char*)d_ws;

  unsigned short* wt   = (unsigned short*)(ws + WT_OFF);
  int* flag            = (int*)(ws + FLAG_OFF);
  int* cnt             = (int*)(ws + CNT_OFF);
  unsigned short* padx = (unsigned short*)(ws + PADX_OFF);

  k_prep<<<452, 256, 0, stream>>>(wfull, wt, pad, cnt, (const unsigned int*)nbr, flag);
  k_rankpadx<<<NCHUNK, 256, 0, stream>>>(x, pad, cnt, padx);
  k_main<<<NBLK3, 1024, 0, stream>>>(padx, wt, nbr, flag, bias, out);
}